// Round 5
// baseline (662.924 us; speedup 1.0000x reference)
//
#include <hip/hip_runtime.h>
#include <hip/hip_bf16.h>
#include <math.h>

// Problem constants
#define BB   8
#define CIN  256
#define HH   64
#define WW   64
#define KK   9
#define OMC  27          // 3*K offset/mask channels
#define HW   (HH*WW)
#define KTOT (CIN*KK)    // 2304 GEMM K
#define NPIX 32          // pixels per block (N tile)
#define SPITCH 296       // LDS sample row pitch in halves (288 + 8 pad)
#define XPITCH 40        // prologue LDS x-tile channel pitch in halves
#define TPITCH 36        // gather tile ch pitch in halves (32 + 4 pad)
#define TROWS  7         // rows h-3..h+3
#define TCOLS  40        // cols w0-3..w0+36
#define TELEM  (TROWS*TCOLS*32)   // 8960 elements per chunk tile

typedef short bf16x8 __attribute__((ext_vector_type(8)));
typedef float f32x4  __attribute__((ext_vector_type(4)));
typedef unsigned short u16x4 __attribute__((ext_vector_type(4)));

__device__ __forceinline__ unsigned short f2bf(float f) {
    union { float f; unsigned int u; } v; v.f = f;
    unsigned int r = v.u + 0x7FFFu + ((v.u >> 16) & 1u);   // RNE
    return (unsigned short)(r >> 16);
}
__device__ __forceinline__ float bf2f(unsigned short u) {
    union { unsigned int i; float f; } c; c.i = ((unsigned int)u) << 16;
    return c.f;
}

// ---------------------------------------------------------------------------
// Kernel 0a: w_dc (fp32 [o][c*9+tap]) -> bf16 wA, TAP-MAJOR chunk-local k:
//   k' = (c>>5)*288 + tap*32 + (c&31);  wA[k'>>3][o][k'&7]
// ---------------------------------------------------------------------------
__global__ __launch_bounds__(256) void wprep_kernel(
    const float* __restrict__ w_dc, unsigned short* __restrict__ wA)
{
    int e = blockIdx.x * 256 + threadIdx.x;          // 256*2304 elements
    int o = e / KTOT;
    int k = e - o * KTOT;
    int c   = k / 9;
    int tap = k - c * 9;
    int kp  = (c >> 5) * 288 + tap * 32 + (c & 31);
    wA[((size_t)(kp >> 3) * 256 + o) * 8 + (kp & 7)] = f2bf(w_dc[e]);
}

// ---------------------------------------------------------------------------
// Kernel 0b: w_om (fp32 [27][256][9]) -> bf16 padded/swizzled:
// wOmA[(((tap*8+cc)*4 + cb)*32 + o)*8 + j], channel c = cc*32+cb*8+j, o<32pad.
// ---------------------------------------------------------------------------
__global__ __launch_bounds__(256) void womprep_kernel(
    const float* __restrict__ w_om, unsigned short* __restrict__ wOmA)
{
    int e = blockIdx.x * 256 + threadIdx.x;          // 73728
    int j  = e & 7;
    int t1 = e >> 3;
    int o  = t1 & 31;
    int t2 = t1 >> 5;
    int cb = t2 & 3;
    int t3 = t2 >> 2;
    int cc = t3 & 7;
    int tap = t3 >> 3;
    int c = cc * 32 + cb * 8 + j;
    float v = (o < OMC) ? w_om[(size_t)o * KTOT + c * 9 + tap] : 0.f;
    wOmA[e] = f2bf(v);
}

// ---------------------------------------------------------------------------
// Fused kernel: om-conv MFMA prologue + LDS-tiled bilinear gather + MFMA GEMM
// Block = (b, h, w-half): M=256 (4 waves x 64 o), N=32 pixels, K=2304.
// ---------------------------------------------------------------------------
__global__ __launch_bounds__(256) void deform_mfma_kernel(
    const float* __restrict__ x, const unsigned short* __restrict__ wOmA,
    const float* __restrict__ b_om,
    const unsigned short* __restrict__ wA, const float* __restrict__ b_dc,
    float* __restrict__ out)
{
    const int bid  = blockIdx.x;         // b*128 + h*2 + wt
    const int b    = bid >> 7;
    const int h    = (bid >> 1) & 63;
    const int w0   = (bid & 1) * NPIX;
    const int t    = threadIdx.x;
    const int wv   = t >> 6;             // wave 0..3
    const int lane = t & 63;
    const int lq   = lane >> 4;          // k-quarter
    const int lm   = lane & 15;

    __shared__ __align__(16) unsigned short sS[NPIX * SPITCH]; // 18.9 KB samples
    __shared__ __align__(16) unsigned short sT[TROWS * TCOLS * TPITCH]; // 20.2 KB x-tile
    __shared__ int    s_off[9 * NPIX];   // global fallback word offset
    __shared__ int    s_dpk[9 * NPIX];   // dtx | dty<<8
    __shared__ int    s_lb [9 * NPIX];   // LDS tile half-base, or -1 -> fallback
    __shared__ float4 s_w4 [9 * NPIX];   // mask-folded bilinear weights

    // Overlays: prologue sX inside sT; som inside sS.
    unsigned short* sX  = sT;                                  // 4080 halves
    float*          som = reinterpret_cast<float*>(sS + 4096); // 864 floats

    const size_t xb_base = (size_t)b * CIN * HW;

    // ================= om-conv prologue =================
    {
        f32x4 accOm = (f32x4)(0.f);
        const int mfp = wv >> 1;         // M-frag (o block of 16)
        const int nfp = wv & 1;          // N-frag (pixel block of 16)
        const int p   = nfp * 16 + lm;   // pixel 0..31
        const bf16x8* wOmV = reinterpret_cast<const bf16x8*>(wOmA);

        for (int cc = 0; cc < 8; ++cc) {
            for (int e = t; e < 3 * 34 * 32; e += 256) {
                int cl  = e / 102;            // 3*34
                int r   = e - cl * 102;
                int row = r / 34;
                int col = r - row * 34;
                int hy = h - 1 + row;
                int wx = w0 - 1 + col;
                float v = 0.f;
                if (hy >= 0 && hy < HH && wx >= 0 && wx < WW)
                    v = x[xb_base + (size_t)(cc * 32 + cl) * HW + hy * WW + wx];
                sX[(row * 34 + col) * XPITCH + cl] = f2bf(v);
            }
            __syncthreads();

#pragma unroll
            for (int tap = 0; tap < 9; ++tap) {
                int kh = tap / 3, kw = tap % 3;
                bf16x8 bf = *reinterpret_cast<const bf16x8*>(
                    &sX[(kh * 34 + p + kw) * XPITCH + lq * 8]);
                bf16x8 af = wOmV[(((tap * 8 + cc) * 4 + lq) * 32) + mfp * 16 + lm];
                accOm = __builtin_amdgcn_mfma_f32_16x16x32_bf16(af, bf, accOm, 0, 0, 0);
            }
            __syncthreads();
        }

#pragma unroll
        for (int r = 0; r < 4; ++r) {
            int o = mfp * 16 + lq * 4 + r;
            if (o < OMC)
                som[o * NPIX + p] = accOm[r] + b_om[o];
        }
    }
    __syncthreads();

    // ========== offset/mask params from som + stage tile for chunk 0 ==========
    for (int e = t; e < 9 * NPIX; e += 256) {
        int tap = e >> 5;
        int pix = e & 31;
        float dy = som[(2 * tap) * NPIX + pix];
        float dx = som[(2 * tap + 1) * NPIX + pix];
        float mv = som[(18 + tap) * NPIX + pix];
        float m  = 1.f / (1.f + expf(-mv));
        float py = (float)(h - 1 + tap / 3) + dy;
        float px = (float)(w0 + pix - 1 + tap % 3) + dx;
        float y0f = floorf(py), x0f = floorf(px);
        float wy1 = py - y0f, wx1 = px - x0f;
        float wy0 = 1.f - wy1, wx0 = 1.f - wx1;
        int y0 = (int)y0f, x0 = (int)x0f;
        int y1 = y0 + 1, x1 = x0 + 1;
        bool yv0 = (y0 >= 0) && (y0 < HH);
        bool yv1 = (y1 >= 0) && (y1 < HH);
        bool xv0 = (x0 >= 0) && (x0 < WW);
        bool xv1 = (x1 >= 0) && (x1 < WW);
        int yc0 = min(max(y0, 0), HH - 1), yc1 = min(max(y1, 0), HH - 1);
        int xc0 = min(max(x0, 0), WW - 1), xc1 = min(max(x1, 0), WW - 1);
        float4 ww;
        ww.x = (yv0 && xv0) ? wy0 * wx0 * m : 0.f;
        ww.y = (yv0 && xv1) ? wy0 * wx1 * m : 0.f;
        ww.z = (yv1 && xv0) ? wy1 * wx0 * m : 0.f;
        ww.w = (yv1 && xv1) ? wy1 * wx1 * m : 0.f;
        s_off[e] = yc0 * WW + xc0;
        s_dpk[e] = (xc1 - xc0) | ((yc1 - yc0) << 8);
        s_w4[e]  = ww;
        // in-tile test (clamped corners within [h-3,h+3] x [w0-3,w0+36])
        bool inT = (yc0 >= h - 3) && (yc1 <= h + 3) &&
                   (xc0 >= w0 - 3) && (xc1 <= w0 + 36);
        int ty0 = yc0 - (h - 3), tx0 = xc0 - (w0 - 3);
        s_lb[e] = inT ? (ty0 * TCOLS + tx0) * TPITCH : -1;
    }
    // stage chunk-0 tile: rows h-3..h+3, cols w0-3..w0+36, ch 0..31 (bf16)
#pragma unroll
    for (int i = 0; i < TELEM / 256; ++i) {
        int e   = t + i * 256;
        int q   = e / TCOLS;             // ch*7 + row
        int col = e - q * TCOLS;
        int chl = q / TROWS;
        int row = q - chl * TROWS;
        int gy = h - 3 + row;
        int gx = w0 - 3 + col;
        float v = 0.f;
        if (gy >= 0 && gy < HH && gx >= 0 && gx < WW)
            v = x[xb_base + (size_t)chl * HW + gy * WW + gx];
        sT[(row * TCOLS + col) * TPITCH + chl] = f2bf(v);
    }
    __syncthreads();

    // ================= main deform GEMM =================
    f32x4 acc[4][2];
#pragma unroll
    for (int i = 0; i < 4; ++i)
#pragma unroll
        for (int j = 0; j < 2; ++j)
            acc[i][j] = (f32x4)(0.f);

    const int pix = lane & 31;           // gather pixel
    const int sub = lane >> 5;           // channel sub-half
    const int clb = wv * 8 + sub * 4;    // 4-channel group base within chunk

    for (int ch = 0; ch < 8; ++ch) {
        // ---- gather from LDS tile (fallback to global for big offsets) ----
#pragma unroll 3
        for (int tap = 0; tap < 9; ++tap) {
            int    idx = tap * NPIX + pix;
            int    lb  = s_lb[idx];
            int    dpk = s_dpk[idx];
            float4 ww  = s_w4[idx];
            int dtx = dpk & 0xFF;
            int dty = dpk >> 8;
            float v[4];
            if (lb >= 0) {
                int b0 = lb + clb;
                int oy = dty * (TCOLS * TPITCH);
                int ox = dtx * TPITCH;
                u16x4 r00 = *reinterpret_cast<const u16x4*>(&sT[b0]);
                u16x4 r01 = *reinterpret_cast<const u16x4*>(&sT[b0 + ox]);
                u16x4 r10 = *reinterpret_cast<const u16x4*>(&sT[b0 + oy]);
                u16x4 r11 = *reinterpret_cast<const u16x4*>(&sT[b0 + oy + ox]);
#pragma unroll
                for (int j = 0; j < 4; ++j)
                    v[j] = ww.x * bf2f(r00[j]) + ww.y * bf2f(r01[j]) +
                           ww.z * bf2f(r10[j]) + ww.w * bf2f(r11[j]);
            } else {
                int off00 = s_off[idx];
                int d01 = dtx, d10 = dty * WW, d11 = d10 + d01;
#pragma unroll
                for (int j = 0; j < 4; ++j) {
                    const float* xc = x + xb_base + (size_t)(ch * 32 + clb + j) * HW;
                    v[j] = ww.x * xc[off00] + ww.y * xc[off00 + d01] +
                           ww.z * xc[off00 + d10] + ww.w * xc[off00 + d11];
                }
            }
            unsigned int pk0 = f2bf(v[0]) | ((unsigned int)f2bf(v[1]) << 16);
            unsigned int pk1 = f2bf(v[2]) | ((unsigned int)f2bf(v[3]) << 16);
            *reinterpret_cast<uint2*>(&sS[pix * SPITCH + tap * 32 + clb]) =
                make_uint2(pk0, pk1);
        }
        __syncthreads();                  // samples ready; sT consumed

        // ---- prefetch next chunk tile (issue loads before MFMA) ----
        float stg[TELEM / 256];
        const bool doStage = (ch < 7);
        if (doStage) {
            const size_t chb = xb_base + (size_t)(ch + 1) * 32 * HW;
#pragma unroll
            for (int i = 0; i < TELEM / 256; ++i) {
                int e   = t + i * 256;
                int q   = e / TCOLS;
                int col = e - q * TCOLS;
                int chl = q / TROWS;
                int row = q - chl * TROWS;
                int gy = h - 3 + row;
                int gx = w0 - 3 + col;
                float v = 0.f;
                if (gy >= 0 && gy < HH && gx >= 0 && gx < WW)
                    v = x[chb + (size_t)chl * HW + gy * WW + gx];
                stg[i] = v;
            }
        }

        // ---- MFMA: wave wv computes o in [wv*64, wv*64+64) ----
        const int kb_base = ch * 36;
        const bf16x8* wAv = reinterpret_cast<const bf16x8*>(wA);
#pragma unroll 1
        for (int ks = 0; ks < 9; ++ks) {
            bf16x8 bfr[2];
#pragma unroll
            for (int nf = 0; nf < 2; ++nf)
                bfr[nf] = *reinterpret_cast<const bf16x8*>(
                    &sS[(nf * 16 + lm) * SPITCH + ks * 32 + lq * 8]);
#pragma unroll
            for (int mf = 0; mf < 4; ++mf) {
                int o  = wv * 64 + mf * 16 + lm;
                int kb = kb_base + ks * 4 + lq;
                bf16x8 af = wAv[(size_t)kb * 256 + o];
#pragma unroll
                for (int nf = 0; nf < 2; ++nf)
                    acc[mf][nf] = __builtin_amdgcn_mfma_f32_16x16x32_bf16(
                        af, bfr[nf], acc[mf][nf], 0, 0, 0);
            }
        }

        // ---- write staged tile (after MFMA; sT free since gather done) ----
        if (doStage) {
#pragma unroll
            for (int i = 0; i < TELEM / 256; ++i) {
                int e   = t + i * 256;
                int q   = e / TCOLS;
                int col = e - q * TCOLS;
                int chl = q / TROWS;
                int row = q - chl * TROWS;
                sT[(row * TCOLS + col) * TPITCH + chl] = f2bf(stg[i]);
            }
        }
        __syncthreads();                  // sS free + next tile ready
    }

    // ---- epilogue: D row = lq*4 + r, col = lm ----
#pragma unroll
    for (int mf = 0; mf < 4; ++mf) {
#pragma unroll
        for (int r = 0; r < 4; ++r) {
            int o = wv * 64 + mf * 16 + lq * 4 + r;
            float bo = b_dc[o];
#pragma unroll
            for (int nf = 0; nf < 2; ++nf) {
                int p = nf * 16 + lm;
                out[((size_t)(b * 256 + o)) * HW + h * WW + w0 + p] = acc[mf][nf][r] + bo;
            }
        }
    }
}

extern "C" void kernel_launch(void* const* d_in, const int* in_sizes, int n_in,
                              void* d_out, int out_size, void* d_ws, size_t ws_size,
                              hipStream_t stream) {
    const float* x    = (const float*)d_in[0];
    const float* w_om = (const float*)d_in[1];
    const float* b_om = (const float*)d_in[2];
    const float* w_dc = (const float*)d_in[3];
    const float* b_dc = (const float*)d_in[4];
    float* out = (float*)d_out;

    unsigned short* wA   = (unsigned short*)d_ws;                    // 1,179,648 B
    unsigned short* wOmA = (unsigned short*)((char*)d_ws + 1179648); //   147,456 B

    wprep_kernel<<<(256 * KTOT) / 256, 256, 0, stream>>>(w_dc, wA);
    womprep_kernel<<<73728 / 256, 256, 0, stream>>>(w_om, wOmA);
    deform_mfma_kernel<<<BB * HH * 2, 256, 0, stream>>>(x, wOmA, b_om, wA, b_dc, out);
}

// Round 6
// 250.780 us; speedup vs baseline: 2.6435x; 2.6435x over previous
//
#include <hip/hip_runtime.h>
#include <hip/hip_bf16.h>
#include <math.h>

// Problem constants
#define BB   8
#define CIN  256
#define HH   64
#define WW   64
#define OMC  27          // 3*K offset/mask channels
#define HW   (HH*WW)
#define KTOT (CIN*9)     // 2304 GEMM K
#define NPIX 32          // pixels per block (N tile)
#define SPITCH 296       // LDS sample row pitch in halves (288 + 8 pad)
#define XPITCH 40        // prologue LDS x-tile channel pitch in halves
#define TROWS  7         // tile rows h-3..h+3
#define TCOLS  40        // tile cols w0-4..w0+35 (16B-aligned global groups)
#define TCH    280       // floats per channel plane (7*40)
#define TFLOATS (32*TCH) // 8960 floats = 35840 B
#define NSTAGE 35        // 1KB wave-instructions per tile (35*64*16B = 35840)

typedef short bf16x8 __attribute__((ext_vector_type(8)));
typedef float f32x4  __attribute__((ext_vector_type(4)));

__device__ __forceinline__ unsigned short f2bf(float f) {
    union { float f; unsigned int u; } v; v.f = f;
    unsigned int r = v.u + 0x7FFFu + ((v.u >> 16) & 1u);   // RNE
    return (unsigned short)(r >> 16);
}

#define GLOAD_LDS16(g, l) __builtin_amdgcn_global_load_lds( \
    (const __attribute__((address_space(1))) void*)(g),     \
    (__attribute__((address_space(3))) void*)(l), 16, 0, 0)

// ---------------------------------------------------------------------------
// Kernel 0a: w_dc (fp32 [o][c*9+tap]) -> bf16 wA, TAP-MAJOR chunk-local k:
//   k' = (c>>5)*288 + tap*32 + (c&31);  wA[k'>>3][o][k'&7]
// ---------------------------------------------------------------------------
__global__ __launch_bounds__(256) void wprep_kernel(
    const float* __restrict__ w_dc, unsigned short* __restrict__ wA)
{
    int e = blockIdx.x * 256 + threadIdx.x;          // 256*2304 elements
    int o = e / KTOT;
    int k = e - o * KTOT;
    int c   = k / 9;
    int tap = k - c * 9;
    int kp  = (c >> 5) * 288 + tap * 32 + (c & 31);
    wA[((size_t)(kp >> 3) * 256 + o) * 8 + (kp & 7)] = f2bf(w_dc[e]);
}

// ---------------------------------------------------------------------------
// Kernel 0b: w_om (fp32 [27][256][9]) -> bf16 padded/swizzled:
// wOmA[(((tap*8+cc)*4 + cb)*32 + o)*8 + j], channel c = cc*32+cb*8+j, o<32pad.
// ---------------------------------------------------------------------------
__global__ __launch_bounds__(256) void womprep_kernel(
    const float* __restrict__ w_om, unsigned short* __restrict__ wOmA)
{
    int e = blockIdx.x * 256 + threadIdx.x;          // 73728
    int j  = e & 7;
    int t1 = e >> 3;
    int o  = t1 & 31;
    int t2 = t1 >> 5;
    int cb = t2 & 3;
    int t3 = t2 >> 2;
    int cc = t3 & 7;
    int tap = t3 >> 3;
    int c = cc * 32 + cb * 8 + j;
    float v = (o < OMC) ? w_om[(size_t)o * KTOT + c * 9 + tap] : 0.f;
    wOmA[e] = f2bf(v);
}

// ---------------------------------------------------------------------------
// Fused kernel: om-conv MFMA prologue + LDS-tile gather + bf16 MFMA GEMM.
// Block = (b, h, w-half): M=256 (4 waves x 64 o), N=32 pixels, K=2304.
// x-tile (fp32, [ch][row][col]) staged via global_load_lds (zero VGPR),
// prefetched for chunk ch+1 under the MFMA of chunk ch.
// ---------------------------------------------------------------------------
__global__ __launch_bounds__(256, 2) void deform_mfma_kernel(
    const float* __restrict__ x, const unsigned short* __restrict__ wOmA,
    const float* __restrict__ b_om,
    const unsigned short* __restrict__ wA, const float* __restrict__ b_dc,
    float* __restrict__ out)
{
    const int bid  = blockIdx.x;         // b*128 + h*2 + wt
    const int b    = bid >> 7;
    const int h    = (bid >> 1) & 63;
    const int w0   = (bid & 1) * NPIX;
    const int t    = threadIdx.x;
    const int wv   = t >> 6;             // wave 0..3
    const int lane = t & 63;
    const int lq   = lane >> 4;          // k-quarter
    const int lm   = lane & 15;

    __shared__ __align__(16) unsigned short sS[NPIX * SPITCH];  // 18.9 KB samples
    __shared__ __align__(16) float sT[TFLOATS];                 // 35.8 KB x-tile
    __shared__ int    s_off[9 * NPIX];   // global fallback word offset
    __shared__ int    s_dpk[9 * NPIX];   // dtx | dty<<8
    __shared__ int    s_lb [9 * NPIX];   // in-plane tile float idx, or -1
    __shared__ float4 s_w4 [9 * NPIX];   // mask-folded bilinear weights

    // Overlays: prologue sX inside sT; som inside sS.
    unsigned short* sX  = reinterpret_cast<unsigned short*>(sT); // 4080 halves
    float*          som = reinterpret_cast<float*>(sS + 4096);   // 864 floats

    const size_t xb_base = (size_t)b * CIN * HW;
    const float* gx_base = x + xb_base;

    // ---- precompute per-thread tile-stage source offsets (9 x 1KB instrs) ----
    int srcOff[9];
#pragma unroll
    for (int i = 0; i < 9; ++i) {
        int wi = wv + i * 4;             // wave-instruction index
        int q  = wi * 64 + lane;         // 16B-chunk index, < 2240
        if (wi < NSTAGE) {
            int ch  = q / 70;
            int rem = q - ch * 70;
            int row = rem / 10;
            int c4  = rem - row * 10;
            int gy  = min(max(h - 3 + row, 0), HH - 1);
            int gx0 = min(max(w0 - 4 + c4 * 4, 0), WW - 4);
            srcOff[i] = ch * HW + gy * WW + gx0;
        } else srcOff[i] = 0;
    }

    // ================= om-conv prologue =================
    {
        f32x4 accOm = (f32x4)(0.f);
        const int mfp = wv >> 1;         // M-frag (o block of 16)
        const int nfp = wv & 1;          // N-frag (pixel block of 16)
        const int p   = nfp * 16 + lm;   // pixel 0..31
        const bf16x8* wOmV = reinterpret_cast<const bf16x8*>(wOmA);

        for (int cc = 0; cc < 8; ++cc) {
            for (int e = t; e < 3 * 34 * 32; e += 256) {
                int cl  = e / 102;            // 3*34
                int r   = e - cl * 102;
                int row = r / 34;
                int col = r - row * 34;
                int hy = h - 1 + row;
                int wx = w0 - 1 + col;
                float v = 0.f;
                if (hy >= 0 && hy < HH && wx >= 0 && wx < WW)
                    v = x[xb_base + (size_t)(cc * 32 + cl) * HW + hy * WW + wx];
                sX[(row * 34 + col) * XPITCH + cl] = f2bf(v);
            }
            __syncthreads();

#pragma unroll
            for (int tap = 0; tap < 9; ++tap) {
                int kh = tap / 3, kw = tap % 3;
                bf16x8 bf = *reinterpret_cast<const bf16x8*>(
                    &sX[(kh * 34 + p + kw) * XPITCH + lq * 8]);
                bf16x8 af = wOmV[(((tap * 8 + cc) * 4 + lq) * 32) + mfp * 16 + lm];
                accOm = __builtin_amdgcn_mfma_f32_16x16x32_bf16(af, bf, accOm, 0, 0, 0);
            }
            __syncthreads();
        }

#pragma unroll
        for (int r = 0; r < 4; ++r) {
            int o = mfp * 16 + lq * 4 + r;
            if (o < OMC)
                som[o * NPIX + p] = accOm[r] + b_om[o];
        }
    }
    __syncthreads();

    // ---- issue tile stage for chunk 0 (DMA flies under params compute) ----
#pragma unroll
    for (int i = 0; i < 9; ++i)
        if (wv + i * 4 < NSTAGE)
            GLOAD_LDS16(gx_base + srcOff[i], (char*)sT + (wv + i * 4) * 1024);
    __builtin_amdgcn_sched_barrier(0);

    // ========== offset/mask params from som ==========
    for (int e = t; e < 9 * NPIX; e += 256) {
        int tap = e >> 5;
        int pix = e & 31;
        float dy = som[(2 * tap) * NPIX + pix];
        float dx = som[(2 * tap + 1) * NPIX + pix];
        float mv = som[(18 + tap) * NPIX + pix];
        float m  = 1.f / (1.f + expf(-mv));
        float py = (float)(h - 1 + tap / 3) + dy;
        float px = (float)(w0 + pix - 1 + tap % 3) + dx;
        float y0f = floorf(py), x0f = floorf(px);
        float wy1 = py - y0f, wx1 = px - x0f;
        float wy0 = 1.f - wy1, wx0 = 1.f - wx1;
        int y0 = (int)y0f, x0 = (int)x0f;
        int y1 = y0 + 1, x1 = x0 + 1;
        bool yv0 = (y0 >= 0) && (y0 < HH);
        bool yv1 = (y1 >= 0) && (y1 < HH);
        bool xv0 = (x0 >= 0) && (x0 < WW);
        bool xv1 = (x1 >= 0) && (x1 < WW);
        int yc0 = min(max(y0, 0), HH - 1), yc1 = min(max(y1, 0), HH - 1);
        int xc0 = min(max(x0, 0), WW - 1), xc1 = min(max(x1, 0), WW - 1);
        float4 ww;
        ww.x = (yv0 && xv0) ? wy0 * wx0 * m : 0.f;
        ww.y = (yv0 && xv1) ? wy0 * wx1 * m : 0.f;
        ww.z = (yv1 && xv0) ? wy1 * wx0 * m : 0.f;
        ww.w = (yv1 && xv1) ? wy1 * wx1 * m : 0.f;
        s_off[e] = yc0 * WW + xc0;
        s_dpk[e] = (xc1 - xc0) | ((yc1 - yc0) << 8);
        s_w4[e]  = ww;
        // in-tile test: clamped corners within rows [h-3,h+3], cols [w0-4,w0+35]
        bool inT = (yc0 >= h - 3) && (yc1 <= h + 3) &&
                   (xc0 >= w0 - 4) && (xc1 <= w0 + 35);
        s_lb[e] = inT ? ((yc0 - (h - 3)) * TCOLS + (xc0 - (w0 - 4))) : -1;
    }
    __syncthreads();   // params ready + chunk-0 tile loaded (vmcnt drained)

    // ================= main deform GEMM =================
    f32x4 acc[4][2];
#pragma unroll
    for (int i = 0; i < 4; ++i)
#pragma unroll
        for (int j = 0; j < 2; ++j)
            acc[i][j] = (f32x4)(0.f);

    const int pix = lane & 31;           // gather pixel
    const int sub = lane >> 5;           // channel sub-half
    const int clb = wv * 8 + sub * 4;    // 4-channel group base within chunk

    for (int ch = 0; ch < 8; ++ch) {
        // ---- gather from fp32 LDS tile (rare global fallback) ----
#pragma unroll 3
        for (int tap = 0; tap < 9; ++tap) {
            int    idx = tap * NPIX + pix;
            int    lb  = s_lb[idx];
            int    dpk = s_dpk[idx];
            float4 ww  = s_w4[idx];
            int dtx = dpk & 0xFF;
            int dty = dpk >> 8;
            float v[4];
            if (lb >= 0) {
                int oy = dty * TCOLS;
                int base = clb * TCH + lb;
#pragma unroll
                for (int j = 0; j < 4; ++j) {
                    const float* p = &sT[base + j * TCH];
                    v[j] = ww.x * p[0] + ww.y * p[dtx] +
                           ww.z * p[oy] + ww.w * p[oy + dtx];
                }
            } else {
                int off00 = s_off[idx];
                int d01 = dtx, d10 = dty * WW, d11 = d10 + d01;
#pragma unroll
                for (int j = 0; j < 4; ++j) {
                    const float* xc = x + xb_base + (size_t)(ch * 32 + clb + j) * HW;
                    v[j] = ww.x * xc[off00] + ww.y * xc[off00 + d01] +
                           ww.z * xc[off00 + d10] + ww.w * xc[off00 + d11];
                }
            }
            unsigned int pk0 = f2bf(v[0]) | ((unsigned int)f2bf(v[1]) << 16);
            unsigned int pk1 = f2bf(v[2]) | ((unsigned int)f2bf(v[3]) << 16);
            *reinterpret_cast<uint2*>(&sS[pix * SPITCH + tap * 32 + clb]) =
                make_uint2(pk0, pk1);
        }
        __syncthreads();                  // sS ready; sT fully consumed

        // ---- issue next chunk's tile DMA (hides under MFMA) ----
        if (ch < 7) {
            const float* gb = gx_base + (size_t)(ch + 1) * 32 * HW;
#pragma unroll
            for (int i = 0; i < 9; ++i)
                if (wv + i * 4 < NSTAGE)
                    GLOAD_LDS16(gb + srcOff[i], (char*)sT + (wv + i * 4) * 1024);
            __builtin_amdgcn_sched_barrier(0);
        }

        // ---- MFMA: wave wv computes o in [wv*64, wv*64+64) ----
        const int kb_base = ch * 36;
        const bf16x8* wAv = reinterpret_cast<const bf16x8*>(wA);
#pragma unroll 1
        for (int ks = 0; ks < 9; ++ks) {
            bf16x8 bfr[2];
#pragma unroll
            for (int nf = 0; nf < 2; ++nf)
                bfr[nf] = *reinterpret_cast<const bf16x8*>(
                    &sS[(nf * 16 + lm) * SPITCH + ks * 32 + lq * 8]);
#pragma unroll
            for (int mf = 0; mf < 4; ++mf) {
                int o  = wv * 64 + mf * 16 + lm;
                int kb = kb_base + ks * 4 + lq;
                bf16x8 af = wAv[(size_t)kb * 256 + o];
#pragma unroll
                for (int nf = 0; nf < 2; ++nf)
                    acc[mf][nf] = __builtin_amdgcn_mfma_f32_16x16x32_bf16(
                        af, bfr[nf], acc[mf][nf], 0, 0, 0);
            }
        }
        __syncthreads();        // MFMA done (sS free) + next tile DMA drained
    }

    // ---- epilogue: D row = lq*4 + r, col = lm ----
#pragma unroll
    for (int mf = 0; mf < 4; ++mf) {
#pragma unroll
        for (int r = 0; r < 4; ++r) {
            int o = wv * 64 + mf * 16 + lq * 4 + r;
            float bo = b_dc[o];
#pragma unroll
            for (int nf = 0; nf < 2; ++nf) {
                int p = nf * 16 + lm;
                out[((size_t)(b * 256 + o)) * HW + h * WW + w0 + p] = acc[mf][nf][r] + bo;
            }
        }
    }
}

extern "C" void kernel_launch(void* const* d_in, const int* in_sizes, int n_in,
                              void* d_out, int out_size, void* d_ws, size_t ws_size,
                              hipStream_t stream) {
    const float* x    = (const float*)d_in[0];
    const float* w_om = (const float*)d_in[1];
    const float* b_om = (const float*)d_in[2];
    const float* w_dc = (const float*)d_in[3];
    const float* b_dc = (const float*)d_in[4];
    float* out = (float*)d_out;

    unsigned short* wA   = (unsigned short*)d_ws;                    // 1,179,648 B
    unsigned short* wOmA = (unsigned short*)((char*)d_ws + 1179648); //   147,456 B

    wprep_kernel<<<(256 * KTOT) / 256, 256, 0, stream>>>(w_dc, wA);
    womprep_kernel<<<73728 / 256, 256, 0, stream>>>(w_om, wOmA);
    deform_mfma_kernel<<<BB * HH * 2, 256, 0, stream>>>(x, wOmA, b_om, wA, b_dc, out);
}

// Round 7
// 250.763 us; speedup vs baseline: 2.6436x; 1.0001x over previous
//
#include <hip/hip_runtime.h>
#include <hip/hip_bf16.h>
#include <math.h>

// Problem constants
#define BB   8
#define CIN  256
#define HH   64
#define WW   64
#define OMC  27          // 3*K offset/mask channels
#define HW   (HH*WW)
#define KTOT (CIN*9)     // 2304 GEMM K
#define NPIX 32          // pixels per block (N tile)
#define SPITCH 296       // LDS sample row pitch in halves (288 + 8 pad)
#define TROWS  7         // tile rows h-3..h+3
#define TCOLS  40        // tile cols w0-4..w0+35 (16B-aligned global groups)
#define TCH    280       // floats per channel plane (7*40)
#define TFLOATS (32*TCH) // 8960 floats = 35840 B
#define NSTAGE 35        // 1KB wave-instructions per main tile
#define NSTAGE3 15       // 1KB wave-instructions per prologue tile (3*10*32/64)

typedef short bf16x8 __attribute__((ext_vector_type(8)));
typedef float f32x4  __attribute__((ext_vector_type(4)));

__device__ __forceinline__ unsigned short f2bf(float f) {
    union { float f; unsigned int u; } v; v.f = f;
    unsigned int r = v.u + 0x7FFFu + ((v.u >> 16) & 1u);   // RNE
    return (unsigned short)(r >> 16);
}

#define GLOAD_LDS16(g, l) __builtin_amdgcn_global_load_lds( \
    (const __attribute__((address_space(1))) void*)(g),     \
    (__attribute__((address_space(3))) void*)(l), 16, 0, 0)

// ---------------------------------------------------------------------------
// Kernel 0a: w_dc (fp32 [o][c*9+tap]) -> bf16 wA, TAP-MAJOR chunk-local k:
//   k' = (c>>5)*288 + tap*32 + (c&31);  wA[k'>>3][o][k'&7]
// ---------------------------------------------------------------------------
__global__ __launch_bounds__(256) void wprep_kernel(
    const float* __restrict__ w_dc, unsigned short* __restrict__ wA)
{
    int e = blockIdx.x * 256 + threadIdx.x;          // 256*2304 elements
    int o = e / KTOT;
    int k = e - o * KTOT;
    int c   = k / 9;
    int tap = k - c * 9;
    int kp  = (c >> 5) * 288 + tap * 32 + (c & 31);
    wA[((size_t)(kp >> 3) * 256 + o) * 8 + (kp & 7)] = f2bf(w_dc[e]);
}

// ---------------------------------------------------------------------------
// Kernel 0b: w_om (fp32 [27][256][9]) -> bf16 padded/swizzled:
// wOmA[(((tap*8+cc)*4 + cb)*32 + o)*8 + j], channel c = cc*32+cb*8+j, o<32pad.
// ---------------------------------------------------------------------------
__global__ __launch_bounds__(256) void womprep_kernel(
    const float* __restrict__ w_om, unsigned short* __restrict__ wOmA)
{
    int e = blockIdx.x * 256 + threadIdx.x;          // 73728
    int j  = e & 7;
    int t1 = e >> 3;
    int o  = t1 & 31;
    int t2 = t1 >> 5;
    int cb = t2 & 3;
    int t3 = t2 >> 2;
    int cc = t3 & 7;
    int tap = t3 >> 3;
    int c = cc * 32 + cb * 8 + j;
    float v = (o < OMC) ? w_om[(size_t)o * KTOT + c * 9 + tap] : 0.f;
    wOmA[e] = f2bf(v);
}

// ---------------------------------------------------------------------------
// Fused kernel. Block = (b, h, w-half): M=256 (4 waves x 64 o), N=32 pixels.
// Pass 1 (om-conv): 3-row fp32 x-tile via global_load_lds, DOUBLE-BUFFERED,
//   MFMA from tile (no scalar staging).
// Pass 2 (gather+GEMM): 7-row fp32 x-tile via global_load_lds prefetched
//   under MFMA; bilinear gather from LDS; bf16 MFMA GEMM.
// ---------------------------------------------------------------------------
__global__ __launch_bounds__(256, 2) void deform_mfma_kernel(
    const float* __restrict__ x, const unsigned short* __restrict__ wOmA,
    const float* __restrict__ b_om,
    const unsigned short* __restrict__ wA, const float* __restrict__ b_dc,
    float* __restrict__ out)
{
    const int bid  = blockIdx.x;         // b*128 + h*2 + wt
    const int b    = bid >> 7;
    const int h    = (bid >> 1) & 63;
    const int w0   = (bid & 1) * NPIX;
    const int t    = threadIdx.x;
    const int wv   = t >> 6;             // wave 0..3
    const int lane = t & 63;
    const int lq   = lane >> 4;          // k-quarter
    const int lm   = lane & 15;

    __shared__ __align__(16) unsigned short sS[NPIX * SPITCH];  // 18.9 KB samples
    __shared__ __align__(16) float sT[TFLOATS];                 // 35.8 KB x-tile
    __shared__ int    s_off[9 * NPIX];   // global fallback word offset
    __shared__ int    s_dpk[9 * NPIX];   // dtx | dty<<8
    __shared__ int    s_lb [9 * NPIX];   // in-plane tile float idx, or -1
    __shared__ float4 s_w4 [9 * NPIX];   // mask-folded bilinear weights

    // som overlay inside sS (pass-1 output, consumed before first gather)
    float* som = reinterpret_cast<float*>(sS + 4096);   // 864 floats

    const size_t xb_base = (size_t)b * CIN * HW;
    const float* gx_base = x + xb_base;

    // ---- per-thread DMA source offsets ----
    // pass-2 main tile: 7 rows x 10 col-groups x 32 ch = 2240 16B chunks
    int srcOff[9];
#pragma unroll
    for (int i = 0; i < 9; ++i) {
        int wi = wv + i * 4;
        int q  = wi * 64 + lane;
        if (wi < NSTAGE) {
            int ch  = q / 70;
            int rem = q - ch * 70;
            int row = rem / 10;
            int c4  = rem - row * 10;
            int gy  = min(max(h - 3 + row, 0), HH - 1);
            int gx0 = min(max(w0 - 4 + c4 * 4, 0), WW - 4);
            srcOff[i] = ch * HW + gy * WW + gx0;
        } else srcOff[i] = 0;
    }
    // pass-1 tile: 3 rows x 10 col-groups x 32 ch = 960 16B chunks
    int srcOff3[4];
#pragma unroll
    for (int i = 0; i < 4; ++i) {
        int wi = wv + i * 4;
        int q  = wi * 64 + lane;
        if (wi < NSTAGE3) {
            int ch  = q / 30;
            int rem = q - ch * 30;
            int row = rem / 10;
            int c4  = rem - row * 10;
            int gy  = min(max(h - 1 + row, 0), HH - 1);
            int gx0 = min(max(w0 - 4 + c4 * 4, 0), WW - 4);
            srcOff3[i] = ch * HW + gy * WW + gx0;
        } else srcOff3[i] = 0;
    }

    // ================= Pass 1: om-conv from DMA'd fp32 tile =================
    {
        f32x4 accOm = (f32x4)(0.f);
        const int mfp = wv >> 1;         // M-frag (o block of 16)
        const int nfp = wv & 1;          // N-frag (pixel block of 16)
        const int p   = nfp * 16 + lm;   // pixel 0..31
        const bf16x8* wOmV = reinterpret_cast<const bf16x8*>(wOmA);
        float* buf0 = sT;                // 3840 floats each
        float* buf1 = sT + 3840;

        // DMA chunk 0 -> buf0
#pragma unroll
        for (int i = 0; i < 4; ++i)
            if (wv + i * 4 < NSTAGE3)
                GLOAD_LDS16(gx_base + srcOff3[i], (char*)buf0 + (wv + i * 4) * 1024);
        __syncthreads();

        for (int cc = 0; cc < 8; ++cc) {
            const float* cur = (cc & 1) ? buf1 : buf0;
            float*       nxt = (cc & 1) ? buf0 : buf1;
            if (cc < 7) {                // prefetch next chunk under MFMA
                const float* gb = gx_base + (size_t)(cc + 1) * 32 * HW;
#pragma unroll
                for (int i = 0; i < 4; ++i)
                    if (wv + i * 4 < NSTAGE3)
                        GLOAD_LDS16(gb + srcOff3[i], (char*)nxt + (wv + i * 4) * 1024);
                __builtin_amdgcn_sched_barrier(0);
            }
#pragma unroll
            for (int tap = 0; tap < 9; ++tap) {
                int kh = tap / 3, kw = tap % 3;
                int hy = h - 1 + kh;
                bool val = (hy >= 0) && (hy < HH) &&
                           ((unsigned)(w0 + p + kw - 1) < WW);  // conv zero-pad
                const float* bp = cur + kh * TCOLS + (p + kw + 3);
                bf16x8 bfr;
#pragma unroll
                for (int j = 0; j < 8; ++j) {
                    float fv = bp[(lq * 8 + j) * 120];
                    bfr[j] = val ? (short)f2bf(fv) : (short)0;
                }
                bf16x8 af = wOmV[(((tap * 8 + cc) * 4 + lq) * 32) + mfp * 16 + lm];
                accOm = __builtin_amdgcn_mfma_f32_16x16x32_bf16(af, bfr, accOm, 0, 0, 0);
            }
            __syncthreads();   // drains next-chunk DMA + protects buffers
        }

#pragma unroll
        for (int r = 0; r < 4; ++r) {
            int o = mfp * 16 + lq * 4 + r;
            if (o < OMC)
                som[o * NPIX + p] = accOm[r] + b_om[o];
        }
    }
    __syncthreads();

    // ---- issue pass-2 tile DMA for chunk 0 (flies under params compute) ----
#pragma unroll
    for (int i = 0; i < 9; ++i)
        if (wv + i * 4 < NSTAGE)
            GLOAD_LDS16(gx_base + srcOff[i], (char*)sT + (wv + i * 4) * 1024);
    __builtin_amdgcn_sched_barrier(0);

    // ========== offset/mask params from som ==========
    for (int e = t; e < 9 * NPIX; e += 256) {
        int tap = e >> 5;
        int pix = e & 31;
        float dy = som[(2 * tap) * NPIX + pix];
        float dx = som[(2 * tap + 1) * NPIX + pix];
        float mv = som[(18 + tap) * NPIX + pix];
        float m  = 1.f / (1.f + expf(-mv));
        float py = (float)(h - 1 + tap / 3) + dy;
        float px = (float)(w0 + pix - 1 + tap % 3) + dx;
        float y0f = floorf(py), x0f = floorf(px);
        float wy1 = py - y0f, wx1 = px - x0f;
        float wy0 = 1.f - wy1, wx0 = 1.f - wx1;
        int y0 = (int)y0f, x0 = (int)x0f;
        int y1 = y0 + 1, x1 = x0 + 1;
        bool yv0 = (y0 >= 0) && (y0 < HH);
        bool yv1 = (y1 >= 0) && (y1 < HH);
        bool xv0 = (x0 >= 0) && (x0 < WW);
        bool xv1 = (x1 >= 0) && (x1 < WW);
        int yc0 = min(max(y0, 0), HH - 1), yc1 = min(max(y1, 0), HH - 1);
        int xc0 = min(max(x0, 0), WW - 1), xc1 = min(max(x1, 0), WW - 1);
        float4 ww;
        ww.x = (yv0 && xv0) ? wy0 * wx0 * m : 0.f;
        ww.y = (yv0 && xv1) ? wy0 * wx1 * m : 0.f;
        ww.z = (yv1 && xv0) ? wy1 * wx0 * m : 0.f;
        ww.w = (yv1 && xv1) ? wy1 * wx1 * m : 0.f;
        s_off[e] = yc0 * WW + xc0;
        s_dpk[e] = (xc1 - xc0) | ((yc1 - yc0) << 8);
        s_w4[e]  = ww;
        // in-tile test: clamped corners within rows [h-3,h+3], cols [w0-4,w0+35]
        bool inT = (yc0 >= h - 3) && (yc1 <= h + 3) &&
                   (xc0 >= w0 - 4) && (xc1 <= w0 + 35);
        s_lb[e] = inT ? ((yc0 - (h - 3)) * TCOLS + (xc0 - (w0 - 4))) : -1;
    }
    __syncthreads();   // params ready + chunk-0 tile loaded (vmcnt drained)

    // ================= Pass 2: main deform GEMM =================
    f32x4 acc[4][2];
#pragma unroll
    for (int i = 0; i < 4; ++i)
#pragma unroll
        for (int j = 0; j < 2; ++j)
            acc[i][j] = (f32x4)(0.f);

    const int pix = lane & 31;           // gather pixel
    const int sub = lane >> 5;           // channel sub-half
    const int clb = wv * 8 + sub * 4;    // 4-channel group base within chunk

    for (int ch = 0; ch < 8; ++ch) {
        // ---- gather from fp32 LDS tile (rare global fallback) ----
#pragma unroll 3
        for (int tap = 0; tap < 9; ++tap) {
            int    idx = tap * NPIX + pix;
            int    lb  = s_lb[idx];
            int    dpk = s_dpk[idx];
            float4 ww  = s_w4[idx];
            int dtx = dpk & 0xFF;
            int dty = dpk >> 8;
            float v[4];
            if (lb >= 0) {
                int oy = dty * TCOLS;
                int base = clb * TCH + lb;
#pragma unroll
                for (int j = 0; j < 4; ++j) {
                    const float* p = &sT[base + j * TCH];
                    v[j] = ww.x * p[0] + ww.y * p[dtx] +
                           ww.z * p[oy] + ww.w * p[oy + dtx];
                }
            } else {
                int off00 = s_off[idx];
                int d01 = dtx, d10 = dty * WW, d11 = d10 + d01;
#pragma unroll
                for (int j = 0; j < 4; ++j) {
                    const float* xc = x + xb_base + (size_t)(ch * 32 + clb + j) * HW;
                    v[j] = ww.x * xc[off00] + ww.y * xc[off00 + d01] +
                           ww.z * xc[off00 + d10] + ww.w * xc[off00 + d11];
                }
            }
            unsigned int pk0 = f2bf(v[0]) | ((unsigned int)f2bf(v[1]) << 16);
            unsigned int pk1 = f2bf(v[2]) | ((unsigned int)f2bf(v[3]) << 16);
            *reinterpret_cast<uint2*>(&sS[pix * SPITCH + tap * 32 + clb]) =
                make_uint2(pk0, pk1);
        }
        __syncthreads();                  // sS ready; sT fully consumed

        // ---- issue next chunk's tile DMA (hides under MFMA) ----
        if (ch < 7) {
            const float* gb = gx_base + (size_t)(ch + 1) * 32 * HW;
#pragma unroll
            for (int i = 0; i < 9; ++i)
                if (wv + i * 4 < NSTAGE)
                    GLOAD_LDS16(gb + srcOff[i], (char*)sT + (wv + i * 4) * 1024);
            __builtin_amdgcn_sched_barrier(0);
        }

        // ---- MFMA: wave wv computes o in [wv*64, wv*64+64) ----
        const int kb_base = ch * 36;
        const bf16x8* wAv = reinterpret_cast<const bf16x8*>(wA);
#pragma unroll 1
        for (int ks = 0; ks < 9; ++ks) {
            bf16x8 bfr[2];
#pragma unroll
            for (int nf = 0; nf < 2; ++nf)
                bfr[nf] = *reinterpret_cast<const bf16x8*>(
                    &sS[(nf * 16 + lm) * SPITCH + ks * 32 + lq * 8]);
#pragma unroll
            for (int mf = 0; mf < 4; ++mf) {
                int o  = wv * 64 + mf * 16 + lm;
                int kb = kb_base + ks * 4 + lq;
                bf16x8 af = wAv[(size_t)kb * 256 + o];
#pragma unroll
                for (int nf = 0; nf < 2; ++nf)
                    acc[mf][nf] = __builtin_amdgcn_mfma_f32_16x16x32_bf16(
                        af, bfr[nf], acc[mf][nf], 0, 0, 0);
            }
        }
        __syncthreads();        // MFMA done (sS free) + next tile DMA drained
    }

    // ---- epilogue: D row = lq*4 + r, col = lm ----
#pragma unroll
    for (int mf = 0; mf < 4; ++mf) {
#pragma unroll
        for (int r = 0; r < 4; ++r) {
            int o = wv * 64 + mf * 16 + lq * 4 + r;
            float bo = b_dc[o];
#pragma unroll
            for (int nf = 0; nf < 2; ++nf) {
                int p = nf * 16 + lm;
                out[((size_t)(b * 256 + o)) * HW + h * WW + w0 + p] = acc[mf][nf][r] + bo;
            }
        }
    }
}

extern "C" void kernel_launch(void* const* d_in, const int* in_sizes, int n_in,
                              void* d_out, int out_size, void* d_ws, size_t ws_size,
                              hipStream_t stream) {
    const float* x    = (const float*)d_in[0];
    const float* w_om = (const float*)d_in[1];
    const float* b_om = (const float*)d_in[2];
    const float* w_dc = (const float*)d_in[3];
    const float* b_dc = (const float*)d_in[4];
    float* out = (float*)d_out;

    unsigned short* wA   = (unsigned short*)d_ws;                    // 1,179,648 B
    unsigned short* wOmA = (unsigned short*)((char*)d_ws + 1179648); //   147,456 B

    wprep_kernel<<<(256 * KTOT) / 256, 256, 0, stream>>>(w_dc, wA);
    womprep_kernel<<<73728 / 256, 256, 0, stream>>>(w_om, wOmA);
    deform_mfma_kernel<<<BB * HH * 2, 256, 0, stream>>>(x, wOmA, b_om, wA, b_dc, out);
}

// Round 8
// 202.848 us; speedup vs baseline: 3.2681x; 1.2362x over previous
//
#include <hip/hip_runtime.h>
#include <hip/hip_bf16.h>
#include <math.h>

// Problem constants
#define BB   8
#define CIN  256
#define HH   64
#define WW   64
#define OMC  27          // 3*K offset/mask channels
#define HW   (HH*WW)
#define KTOT (CIN*9)     // 2304 GEMM K
#define NPIX 32          // pixels per block (N tile)
#define SPITCH 296       // LDS sample row pitch in halves (288 + 8 pad)
#define TCOLS  40        // tile cols w0-4..w0+35 (16B-aligned global groups)
// pass-2 gather tile: 5 rows h-2..h+2, fp32 [ch][row][col]
#define TCH5   200       // floats per channel plane (5*40)
#define NST5   25        // 1KB wave-instructions per tile (5*10*32/64)
// pass-1 conv tile: 3 rows h-1..h+1
#define TCH3   120       // floats per channel plane (3*40)
#define NST3   15        // 1KB wave-instructions per tile (3*10*32/64)

typedef short bf16x8 __attribute__((ext_vector_type(8)));
typedef float f32x4  __attribute__((ext_vector_type(4)));

__device__ __forceinline__ unsigned short f2bf(float f) {
    union { float f; unsigned int u; } v; v.f = f;
    unsigned int r = v.u + 0x7FFFu + ((v.u >> 16) & 1u);   // RNE
    return (unsigned short)(r >> 16);
}

#define GLOAD_LDS16(g, l) __builtin_amdgcn_global_load_lds( \
    (const __attribute__((address_space(1))) void*)(g),     \
    (__attribute__((address_space(3))) void*)(l), 16, 0, 0)

// ---------------------------------------------------------------------------
// Kernel 0a: w_dc (fp32 [o][c*9+tap]) -> bf16 wA, TAP-MAJOR chunk-local k:
//   k' = (c>>5)*288 + tap*32 + (c&31);  wA[k'>>3][o][k'&7]
// ---------------------------------------------------------------------------
__global__ __launch_bounds__(256) void wprep_kernel(
    const float* __restrict__ w_dc, unsigned short* __restrict__ wA)
{
    int e = blockIdx.x * 256 + threadIdx.x;          // 256*2304 elements
    int o = e / KTOT;
    int k = e - o * KTOT;
    int c   = k / 9;
    int tap = k - c * 9;
    int kp  = (c >> 5) * 288 + tap * 32 + (c & 31);
    wA[((size_t)(kp >> 3) * 256 + o) * 8 + (kp & 7)] = f2bf(w_dc[e]);
}

// ---------------------------------------------------------------------------
// Kernel 0b: w_om (fp32 [27][256][9]) -> bf16 padded/swizzled:
// wOmA[(((tap*8+cc)*4 + cb)*32 + o)*8 + j], channel c = cc*32+cb*8+j, o<32pad.
// ---------------------------------------------------------------------------
__global__ __launch_bounds__(256) void womprep_kernel(
    const float* __restrict__ w_om, unsigned short* __restrict__ wOmA)
{
    int e = blockIdx.x * 256 + threadIdx.x;          // 73728
    int j  = e & 7;
    int t1 = e >> 3;
    int o  = t1 & 31;
    int t2 = t1 >> 5;
    int cb = t2 & 3;
    int t3 = t2 >> 2;
    int cc = t3 & 7;
    int tap = t3 >> 3;
    int c = cc * 32 + cb * 8 + j;
    float v = (o < OMC) ? w_om[(size_t)o * KTOT + c * 9 + tap] : 0.f;
    wOmA[e] = f2bf(v);
}

// ---------------------------------------------------------------------------
// Fused kernel, 512 threads (8 waves). M=256, N=32 pixels, K=2304.
// Pass 1: om-conv from DMA'd 3-row fp32 tile (double-buffered).
// Pass 2: bilinear gather from DMA'd 5-row fp32 tile (global fallback for
//         |offset| tail), bf16 MFMA GEMM. LDS ~52.6 KB -> 3 blocks/CU.
// ---------------------------------------------------------------------------
__global__ __launch_bounds__(512, 6) void deform_mfma_kernel(
    const float* __restrict__ x, const unsigned short* __restrict__ wOmA,
    const float* __restrict__ b_om,
    const unsigned short* __restrict__ wA, const float* __restrict__ b_dc,
    float* __restrict__ out)
{
    const int bid  = blockIdx.x;         // b*128 + h*2 + wt
    const int b    = bid >> 7;
    const int h    = (bid >> 1) & 63;
    const int w0   = (bid & 1) * NPIX;
    const int t    = threadIdx.x;
    const int wv   = t >> 6;             // wave 0..7
    const int lane = t & 63;
    const int lq   = lane >> 4;          // k-quarter
    const int lm   = lane & 15;

    __shared__ __align__(16) unsigned short sS[NPIX * SPITCH];  // 18944 B
    __shared__ __align__(16) float sT[32 * TCH5];               // 25600 B
    __shared__ int    s_off[9 * NPIX];   // global fallback word offset
    __shared__ int    s_dpk[9 * NPIX];   // dtx | dty<<8
    __shared__ int    s_lb [9 * NPIX];   // in-plane tile float idx, or -1
    __shared__ float4 s_w4 [9 * NPIX];   // mask-folded bilinear weights

    // Overlays: som on s_w4 (864 fl <= 1152); pass-1 dbuf: buf0=sT, buf1=sS.
    float* som  = reinterpret_cast<float*>(s_w4);
    float* buf0 = sT;
    float* buf1 = reinterpret_cast<float*>(sS);   // 3840 fl <= 4736

    const size_t xb_base = (size_t)b * CIN * HW;
    const float* gx_base = x + xb_base;

    // ---- per-lane DMA source offsets ----
    // pass-1 tile: 3 rows x 10 col-groups x 32 ch = 960 16B chunks
    int srcOff3[2];
#pragma unroll
    for (int i = 0; i < 2; ++i) {
        int wi = wv + i * 8;
        int q  = wi * 64 + lane;
        if (wi < NST3) {
            int ch  = q / 30;
            int rem = q - ch * 30;
            int row = rem / 10;
            int c4  = rem - row * 10;
            int gy  = min(max(h - 1 + row, 0), HH - 1);
            int gx0 = min(max(w0 - 4 + c4 * 4, 0), WW - 4);
            srcOff3[i] = ch * HW + gy * WW + gx0;
        } else srcOff3[i] = 0;
    }
    // pass-2 tile: 5 rows x 10 col-groups x 32 ch = 1600 16B chunks
    int srcOff5[4];
#pragma unroll
    for (int i = 0; i < 4; ++i) {
        int wi = wv + i * 8;
        int q  = wi * 64 + lane;
        if (wi < NST5) {
            int ch  = q / 50;
            int rem = q - ch * 50;
            int row = rem / 10;
            int c4  = rem - row * 10;
            int gy  = min(max(h - 2 + row, 0), HH - 1);
            int gx0 = min(max(w0 - 4 + c4 * 4, 0), WW - 4);
            srcOff5[i] = ch * HW + gy * WW + gx0;
        } else srcOff5[i] = 0;
    }

    // ================= Pass 1: om-conv from DMA'd fp32 tile =================
    {
        f32x4 accOm = (f32x4)(0.f);
        const int mfp = (wv >> 1) & 1;   // M-frag (o block of 16)
        const int nfp = wv & 1;          // N-frag (pixel block of 16)
        const int p   = nfp * 16 + lm;   // pixel 0..31
        const bf16x8* wOmV = reinterpret_cast<const bf16x8*>(wOmA);

        // DMA chunk 0 -> buf0
#pragma unroll
        for (int i = 0; i < 2; ++i)
            if (wv + i * 8 < NST3)
                GLOAD_LDS16(gx_base + srcOff3[i], (char*)buf0 + (wv + i * 8) * 1024);
        __syncthreads();

        for (int cc = 0; cc < 8; ++cc) {
            const float* cur = (cc & 1) ? buf1 : buf0;
            float*       nxt = (cc & 1) ? buf0 : buf1;
            if (cc < 7) {                // prefetch next chunk under MFMA
                const float* gb = gx_base + (size_t)(cc + 1) * 32 * HW;
#pragma unroll
                for (int i = 0; i < 2; ++i)
                    if (wv + i * 8 < NST3)
                        GLOAD_LDS16(gb + srcOff3[i], (char*)nxt + (wv + i * 8) * 1024);
                __builtin_amdgcn_sched_barrier(0);
            }
#pragma unroll
            for (int tap = 0; tap < 9; ++tap) {
                int kh = tap / 3, kw = tap % 3;
                int hy = h - 1 + kh;
                bool val = (hy >= 0) && (hy < HH) &&
                           ((unsigned)(w0 + p + kw - 1) < WW);  // conv zero-pad
                const float* bp = cur + kh * TCOLS + (p + kw + 3);
                bf16x8 bfr;
#pragma unroll
                for (int j = 0; j < 8; ++j) {
                    float fv = bp[(lq * 8 + j) * TCH3];
                    bfr[j] = val ? (short)f2bf(fv) : (short)0;
                }
                bf16x8 af = wOmV[(((tap * 8 + cc) * 4 + lq) * 32) + mfp * 16 + lm];
                accOm = __builtin_amdgcn_mfma_f32_16x16x32_bf16(af, bfr, accOm, 0, 0, 0);
            }
            __syncthreads();   // drains next-chunk DMA + protects buffers
        }

        if (wv < 4) {          // waves 4-7 computed duplicates; one copy writes
#pragma unroll
            for (int r = 0; r < 4; ++r) {
                int o = mfp * 16 + lq * 4 + r;
                if (o < OMC)
                    som[o * NPIX + p] = accOm[r] + b_om[o];
            }
        }
    }
    __syncthreads();           // som visible

    // ---- issue pass-2 chunk-0 tile DMA (flies under params compute) ----
#pragma unroll
    for (int i = 0; i < 4; ++i)
        if (wv + i * 8 < NST5)
            GLOAD_LDS16(gx_base + srcOff5[i], (char*)sT + (wv + i * 8) * 1024);
    __builtin_amdgcn_sched_barrier(0);

    // ========== offset/mask params from som (t < 288, one entry each) ==========
    int   p_off = 0, p_dpk = 0, p_lb = -1;
    float4 p_w4 = make_float4(0.f, 0.f, 0.f, 0.f);
    if (t < 9 * NPIX) {
        int tap = t >> 5;
        int pix = t & 31;
        float dy = som[(2 * tap) * NPIX + pix];
        float dx = som[(2 * tap + 1) * NPIX + pix];
        float mv = som[(18 + tap) * NPIX + pix];
        float m  = 1.f / (1.f + expf(-mv));
        float py = (float)(h - 1 + tap / 3) + dy;
        float px = (float)(w0 + pix - 1 + tap % 3) + dx;
        float y0f = floorf(py), x0f = floorf(px);
        float wy1 = py - y0f, wx1 = px - x0f;
        float wy0 = 1.f - wy1, wx0 = 1.f - wx1;
        int y0 = (int)y0f, x0 = (int)x0f;
        int y1 = y0 + 1, x1 = x0 + 1;
        bool yv0 = (y0 >= 0) && (y0 < HH);
        bool yv1 = (y1 >= 0) && (y1 < HH);
        bool xv0 = (x0 >= 0) && (x0 < WW);
        bool xv1 = (x1 >= 0) && (x1 < WW);
        int yc0 = min(max(y0, 0), HH - 1), yc1 = min(max(y1, 0), HH - 1);
        int xc0 = min(max(x0, 0), WW - 1), xc1 = min(max(x1, 0), WW - 1);
        p_w4.x = (yv0 && xv0) ? wy0 * wx0 * m : 0.f;
        p_w4.y = (yv0 && xv1) ? wy0 * wx1 * m : 0.f;
        p_w4.z = (yv1 && xv0) ? wy1 * wx0 * m : 0.f;
        p_w4.w = (yv1 && xv1) ? wy1 * wx1 * m : 0.f;
        p_off = yc0 * WW + xc0;
        p_dpk = (xc1 - xc0) | ((yc1 - yc0) << 8);
        // in-tile test: rows [h-2,h+2], cols [w0-4,w0+35]
        bool inT = (yc0 >= h - 2) && (yc1 <= h + 2) &&
                   (xc0 >= w0 - 4) && (xc1 <= w0 + 35);
        p_lb = inT ? ((yc0 - (h - 2)) * TCOLS + (xc0 - (w0 - 4))) : -1;
    }
    __syncthreads();           // all som reads done before s_w4 overwritten
    if (t < 9 * NPIX) {
        s_off[t] = p_off;
        s_dpk[t] = p_dpk;
        s_lb[t]  = p_lb;
        s_w4[t]  = p_w4;
    }
    __syncthreads();           // params ready + chunk-0 tile loaded

    // ================= Pass 2: main deform GEMM =================
    f32x4 acc[2][2];
#pragma unroll
    for (int i = 0; i < 2; ++i)
#pragma unroll
        for (int j = 0; j < 2; ++j)
            acc[i][j] = (f32x4)(0.f);

    const int pix  = t & 31;             // gather pixel
    const int slot = t >> 5;             // 0..15 channel slot (2 ch each)
    const int clb2 = slot * 2;

    for (int ch = 0; ch < 8; ++ch) {
        // ---- gather from fp32 LDS tile (rare global fallback) ----
#pragma unroll 3
        for (int tap = 0; tap < 9; ++tap) {
            int    idx = tap * NPIX + pix;
            int    lb  = s_lb[idx];
            int    dpk = s_dpk[idx];
            float4 ww  = s_w4[idx];
            int dtx = dpk & 0xFF;
            int dty = dpk >> 8;
            float v[2];
            if (lb >= 0) {
                int oy = dty * TCOLS;
                int base = clb2 * TCH5 + lb;
#pragma unroll
                for (int j = 0; j < 2; ++j) {
                    const float* pp = &sT[base + j * TCH5];
                    v[j] = ww.x * pp[0] + ww.y * pp[dtx] +
                           ww.z * pp[oy] + ww.w * pp[oy + dtx];
                }
            } else {
                int off00 = s_off[idx];
                int d01 = dtx, d10 = dty * WW, d11 = d10 + d01;
#pragma unroll
                for (int j = 0; j < 2; ++j) {
                    const float* xc = x + xb_base + (size_t)(ch * 32 + clb2 + j) * HW;
                    v[j] = ww.x * xc[off00] + ww.y * xc[off00 + d01] +
                           ww.z * xc[off00 + d10] + ww.w * xc[off00 + d11];
                }
            }
            unsigned int pk = f2bf(v[0]) | ((unsigned int)f2bf(v[1]) << 16);
            *reinterpret_cast<unsigned int*>(
                &sS[pix * SPITCH + tap * 32 + clb2]) = pk;
        }
        __syncthreads();                  // sS ready; sT fully consumed

        // ---- issue next chunk's tile DMA (hides under MFMA) ----
        if (ch < 7) {
            const float* gb = gx_base + (size_t)(ch + 1) * 32 * HW;
#pragma unroll
            for (int i = 0; i < 4; ++i)
                if (wv + i * 8 < NST5)
                    GLOAD_LDS16(gb + srcOff5[i], (char*)sT + (wv + i * 8) * 1024);
            __builtin_amdgcn_sched_barrier(0);
        }

        // ---- MFMA: wave wv computes o in [wv*32, wv*32+32) ----
        const int kb_base = ch * 36;
        const bf16x8* wAv = reinterpret_cast<const bf16x8*>(wA);
#pragma unroll 1
        for (int ks = 0; ks < 9; ++ks) {
            bf16x8 bfr[2];
#pragma unroll
            for (int nf = 0; nf < 2; ++nf)
                bfr[nf] = *reinterpret_cast<const bf16x8*>(
                    &sS[(nf * 16 + lm) * SPITCH + ks * 32 + lq * 8]);
#pragma unroll
            for (int mf = 0; mf < 2; ++mf) {
                int o  = wv * 32 + mf * 16 + lm;
                int kb = kb_base + ks * 4 + lq;
                bf16x8 af = wAv[(size_t)kb * 256 + o];
#pragma unroll
                for (int nf = 0; nf < 2; ++nf)
                    acc[mf][nf] = __builtin_amdgcn_mfma_f32_16x16x32_bf16(
                        af, bfr[nf], acc[mf][nf], 0, 0, 0);
            }
        }
        __syncthreads();        // MFMA done (sS free) + next tile DMA drained
    }

    // ---- epilogue: D row = lq*4 + r, col = lm ----
#pragma unroll
    for (int mf = 0; mf < 2; ++mf) {
#pragma unroll
        for (int r = 0; r < 4; ++r) {
            int o = wv * 32 + mf * 16 + lq * 4 + r;
            float bo = b_dc[o];
#pragma unroll
            for (int nf = 0; nf < 2; ++nf) {
                int p = nf * 16 + lm;
                out[((size_t)(b * 256 + o)) * HW + h * WW + w0 + p] = acc[mf][nf][r] + bo;
            }
        }
    }
}

extern "C" void kernel_launch(void* const* d_in, const int* in_sizes, int n_in,
                              void* d_out, int out_size, void* d_ws, size_t ws_size,
                              hipStream_t stream) {
    const float* x    = (const float*)d_in[0];
    const float* w_om = (const float*)d_in[1];
    const float* b_om = (const float*)d_in[2];
    const float* w_dc = (const float*)d_in[3];
    const float* b_dc = (const float*)d_in[4];
    float* out = (float*)d_out;

    unsigned short* wA   = (unsigned short*)d_ws;                    // 1,179,648 B
    unsigned short* wOmA = (unsigned short*)((char*)d_ws + 1179648); //   147,456 B

    wprep_kernel<<<(256 * KTOT) / 256, 256, 0, stream>>>(w_dc, wA);
    womprep_kernel<<<73728 / 256, 256, 0, stream>>>(w_om, wOmA);
    deform_mfma_kernel<<<BB * HH * 2, 512, 0, stream>>>(x, wOmA, b_om, wA, b_dc, out);
}

// Round 9
// 180.993 us; speedup vs baseline: 3.6627x; 1.1208x over previous
//
#include <hip/hip_runtime.h>
#include <hip/hip_bf16.h>
#include <math.h>

// Problem constants
#define BB   8
#define CIN  256
#define HH   64
#define WW   64
#define OMC  27          // 3*K offset/mask channels
#define HW   (HH*WW)
#define KTOT (CIN*9)     // 2304 GEMM K
#define NPIX 32          // pixels per block (N tile)
#define SPITCH 296       // LDS sample row pitch in halves (288 + 8 pad)
#define TCOLS  40        // tile cols w0-4..w0+35 (16B-aligned global groups)
// pass-2 gather tile: 5 rows h-2..h+2, fp32 [ch][row][col]
#define TCH5   200       // floats per channel plane (5*40)
#define NST5   25        // 1KB wave-instructions per tile (5*10*32/64)
// pass-1 bf16 tile: [3*34 rc][40 ch-pitch], 4080 halves per buffer
#define XP1    40

typedef short bf16x8 __attribute__((ext_vector_type(8)));
typedef float f32x4  __attribute__((ext_vector_type(4)));

__device__ __forceinline__ unsigned short f2bf(float f) {
    union { float f; unsigned int u; } v; v.f = f;
    unsigned int r = v.u + 0x7FFFu + ((v.u >> 16) & 1u);   // RNE
    return (unsigned short)(r >> 16);
}

#define GLOAD_LDS16(g, l) __builtin_amdgcn_global_load_lds( \
    (const __attribute__((address_space(1))) void*)(g),     \
    (__attribute__((address_space(3))) void*)(l), 16, 0, 0)

// ---------------------------------------------------------------------------
// Kernel 0a: w_dc (fp32 [o][c*9+tap]) -> bf16 wA, TAP-MAJOR chunk-local k:
//   k' = (c>>5)*288 + tap*32 + (c&31);  wA[k'>>3][o][k'&7]
// ---------------------------------------------------------------------------
__global__ __launch_bounds__(256) void wprep_kernel(
    const float* __restrict__ w_dc, unsigned short* __restrict__ wA)
{
    int e = blockIdx.x * 256 + threadIdx.x;          // 256*2304 elements
    int o = e / KTOT;
    int k = e - o * KTOT;
    int c   = k / 9;
    int tap = k - c * 9;
    int kp  = (c >> 5) * 288 + tap * 32 + (c & 31);
    wA[((size_t)(kp >> 3) * 256 + o) * 8 + (kp & 7)] = f2bf(w_dc[e]);
}

// ---------------------------------------------------------------------------
// Kernel 0b: w_om (fp32 [27][256][9]) -> bf16 padded/swizzled:
// wOmA[(((tap*8+cc)*4 + cb)*32 + o)*8 + j], channel c = cc*32+cb*8+j, o<32pad.
// ---------------------------------------------------------------------------
__global__ __launch_bounds__(256) void womprep_kernel(
    const float* __restrict__ w_om, unsigned short* __restrict__ wOmA)
{
    int e = blockIdx.x * 256 + threadIdx.x;          // 73728
    int j  = e & 7;
    int t1 = e >> 3;
    int o  = t1 & 31;
    int t2 = t1 >> 5;
    int cb = t2 & 3;
    int t3 = t2 >> 2;
    int cc = t3 & 7;
    int tap = t3 >> 3;
    int c = cc * 32 + cb * 8 + j;
    float v = (o < OMC) ? w_om[(size_t)o * KTOT + c * 9 + tap] : 0.f;
    wOmA[e] = f2bf(v);
}

// ---------------------------------------------------------------------------
// Fused kernel, 512 threads (8 waves). M=256, N=32 pixels, K=2304.
// Pass 1: om-conv from a bf16 [rc][ch] tile (dbuf, b128 frags, 1 barrier/chunk)
// Pass 2: weight-folded bilinear gather from DMA'd 5-row fp32 tile
//         (read2-pair reads, packed params), bf16 MFMA GEMM.
// ---------------------------------------------------------------------------
__global__ __launch_bounds__(512, 6) void deform_mfma_kernel(
    const float* __restrict__ x, const unsigned short* __restrict__ wOmA,
    const float* __restrict__ b_om,
    const unsigned short* __restrict__ wA, const float* __restrict__ b_dc,
    float* __restrict__ out)
{
    const int bid  = blockIdx.x;         // b*128 + h*2 + wt
    const int b    = bid >> 7;
    const int h    = (bid >> 1) & 63;
    const int w0   = (bid & 1) * NPIX;
    const int t    = threadIdx.x;
    const int wv   = t >> 6;             // wave 0..7
    const int lane = t & 63;
    const int lq   = lane >> 4;          // k-quarter
    const int lm   = lane & 15;

    __shared__ __align__(16) unsigned short sS[NPIX * SPITCH];  // 18944 B
    __shared__ __align__(16) float sT[32 * TCH5 + 64];          // 25856 B
    __shared__ int    s_lbp[9 * NPIX];   // packed: lb | dtx<<8 | dty<<9 | off<<10 | inT-sign
    __shared__ float4 s_w4 [9 * NPIX];   // clamp-folded bilinear weights

    // Overlays: som on s_w4; pass-1 bf16 dbuf inside sT (2 x 4080 halves).
    float* som  = reinterpret_cast<float*>(s_w4);
    unsigned short* bufA = reinterpret_cast<unsigned short*>(sT);
    unsigned short* bufB = bufA + 4080;

    const size_t xb_base = (size_t)b * CIN * HW;
    const float* gx_base = x + xb_base;

    // pass-2 tile DMA offsets: 5 rows x 10 col-groups x 32 ch = 1600 16B chunks
    int srcOff5[4];
#pragma unroll
    for (int i = 0; i < 4; ++i) {
        int wi = wv + i * 8;
        int q  = wi * 64 + lane;
        if (wi < NST5) {
            int ch  = q / 50;
            int rem = q - ch * 50;
            int row = rem / 10;
            int c4  = rem - row * 10;
            int gy  = min(max(h - 2 + row, 0), HH - 1);
            int gx0 = min(max(w0 - 4 + c4 * 4, 0), WW - 4);
            srcOff5[i] = ch * HW + gy * WW + gx0;
        } else srcOff5[i] = 0;
    }

    // ================= Pass 1: om-conv (bf16 tile, b128 frags) =================
    {
        f32x4 accOm = (f32x4)(0.f);
        const int mfp = (wv >> 1) & 1;   // M-frag (o block of 16)
        const int nfp = wv & 1;          // N-frag (pixel block of 16)
        const int p   = nfp * 16 + lm;   // pixel 0..31
        const bf16x8* wOmV = reinterpret_cast<const bf16x8*>(wOmA);

        // stage: rows h-1..h+1 x cols w0-1..w0+32 (34) x 32 ch, bf16,
        // layout dst[rc*40 + ch], rc = row*34+col. Zero-pad baked in.
        auto stage1 = [&](int cc, unsigned short* dst) {
            const float* gch = gx_base + (size_t)cc * 32 * HW;
#pragma unroll
            for (int i = 0; i < 7; ++i) {
                int e = t + i * 512;
                if (e < 3264) {
                    int cl  = e / 102;
                    int rc  = e - cl * 102;
                    int row = rc / 34;
                    int col = rc - row * 34;
                    int gy  = h - 1 + row;
                    int gxx = w0 - 1 + col;
                    float v = 0.f;
                    if (gy >= 0 && gy < HH && (unsigned)gxx < WW)
                        v = gch[cl * HW + gy * WW + gxx];
                    dst[rc * XP1 + cl] = f2bf(v);
                }
            }
        };

        stage1(0, bufA);
        __syncthreads();
        for (int cc = 0; cc < 8; ++cc) {
            unsigned short* cur = (cc & 1) ? bufB : bufA;
            unsigned short* nxt = (cc & 1) ? bufA : bufB;
            if (cc < 7) stage1(cc + 1, nxt);      // loads issue early, hide under MFMA
#pragma unroll
            for (int tap = 0; tap < 9; ++tap) {
                int kh = tap / 3, kw = tap % 3;
                bf16x8 bfr = *reinterpret_cast<const bf16x8*>(
                    &cur[(kh * 34 + p + kw) * XP1 + lq * 8]);
                bf16x8 af = wOmV[(((tap * 8 + cc) * 4 + lq) * 32) + mfp * 16 + lm];
                accOm = __builtin_amdgcn_mfma_f32_16x16x32_bf16(af, bfr, accOm, 0, 0, 0);
            }
            __syncthreads();
        }

        if (wv < 4) {          // waves 4-7 computed duplicates; one copy writes
#pragma unroll
            for (int r = 0; r < 4; ++r) {
                int o = mfp * 16 + lq * 4 + r;
                if (o < OMC)
                    som[o * NPIX + p] = accOm[r] + b_om[o];
            }
        }
    }
    __syncthreads();           // som visible

    // ---- issue pass-2 chunk-0 tile DMA (flies under params compute) ----
#pragma unroll
    for (int i = 0; i < 4; ++i)
        if (wv + i * 8 < NST5)
            GLOAD_LDS16(gx_base + srcOff5[i], (char*)sT + (wv + i * 8) * 1024);
    __builtin_amdgcn_sched_barrier(0);

    // ========== offset/mask params from som (t < 288, one entry each) ==========
    int   p_pk = 0;
    float4 p_w4 = make_float4(0.f, 0.f, 0.f, 0.f);
    if (t < 9 * NPIX) {
        int tap = t >> 5;
        int pix = t & 31;
        float dy = som[(2 * tap) * NPIX + pix];
        float dx = som[(2 * tap + 1) * NPIX + pix];
        float mv = som[(18 + tap) * NPIX + pix];
        float m  = 1.f / (1.f + expf(-mv));
        float py = (float)(h - 1 + tap / 3) + dy;
        float px = (float)(w0 + pix - 1 + tap % 3) + dx;
        float y0f = floorf(py), x0f = floorf(px);
        float wy1 = py - y0f, wx1 = px - x0f;
        float wy0 = 1.f - wy1, wx0 = 1.f - wx1;
        int y0 = (int)y0f, x0 = (int)x0f;
        int y1 = y0 + 1, x1 = x0 + 1;
        bool yv0 = (y0 >= 0) && (y0 < HH);
        bool yv1 = (y1 >= 0) && (y1 < HH);
        bool xv0 = (x0 >= 0) && (x0 < WW);
        bool xv1 = (x1 >= 0) && (x1 < WW);
        int yc0 = min(max(y0, 0), HH - 1), yc1 = min(max(y1, 0), HH - 1);
        int xc0 = min(max(x0, 0), WW - 1), xc1 = min(max(x1, 0), WW - 1);
        p_w4.x = (yv0 && xv0) ? wy0 * wx0 * m : 0.f;
        p_w4.y = (yv0 && xv1) ? wy0 * wx1 * m : 0.f;
        p_w4.z = (yv1 && xv0) ? wy1 * wx0 * m : 0.f;
        p_w4.w = (yv1 && xv1) ? wy1 * wx1 * m : 0.f;
        // fold clamp-duplicate corners into weights (exact: duplicated coord)
        if (xc1 == xc0) { p_w4.x += p_w4.y; p_w4.y = 0.f;
                          p_w4.z += p_w4.w; p_w4.w = 0.f; }
        if (yc1 == yc0) { p_w4.x += p_w4.z; p_w4.z = 0.f;
                          p_w4.y += p_w4.w; p_w4.w = 0.f; }
        bool inT = (yc0 >= h - 2) && (yc1 <= h + 2) &&
                   (xc0 >= w0 - 4) && (xc1 <= w0 + 35);
        int lb = (yc0 - (h - 2)) * TCOLS + (xc0 - (w0 - 4));
        p_pk = (lb & 0xFF) | ((xc1 - xc0) << 8) | ((yc1 - yc0) << 9)
             | ((yc0 * WW + xc0) << 10);
        if (!inT) p_pk |= (int)0x80000000;
    }
    // zero the sT overrun pad (read with weight 0 by folded tile path)
    if (t >= 448) sT[32 * TCH5 + (t - 448)] = 0.f;
    __syncthreads();           // all som reads done before s_w4 overwritten
    if (t < 9 * NPIX) {
        s_lbp[t] = p_pk;
        s_w4[t]  = p_w4;
    }
    __syncthreads();           // params ready + chunk-0 tile loaded

    // ================= Pass 2: main deform GEMM =================
    f32x4 acc[2][2];
#pragma unroll
    for (int i = 0; i < 2; ++i)
#pragma unroll
        for (int j = 0; j < 2; ++j)
            acc[i][j] = (f32x4)(0.f);

    const int pix  = t & 31;             // gather pixel
    const int slot = t >> 5;             // 0..15 channel slot (2 ch each)
    const int clb2 = slot * 2;

    for (int ch = 0; ch < 8; ++ch) {
        // ---- gather: folded weights, unconditional read2-pairs ----
#pragma unroll 3
        for (int tap = 0; tap < 9; ++tap) {
            int    idx = tap * NPIX + pix;
            int    pk  = s_lbp[idx];
            float4 ww  = s_w4[idx];
            float v0, v1;
            if (pk >= 0) {
                const float* pp = &sT[clb2 * TCH5 + (pk & 0xFF)];
                v0 = ww.x * pp[0]     + ww.y * pp[1]
                   + ww.z * pp[TCOLS] + ww.w * pp[TCOLS + 1];
                const float* qq = pp + TCH5;
                v1 = ww.x * qq[0]     + ww.y * qq[1]
                   + ww.z * qq[TCOLS] + ww.w * qq[TCOLS + 1];
            } else {
                int off00 = (pk >> 10) & 0xFFF;
                int d01 = (pk >> 8) & 1;
                int d10 = ((pk >> 9) & 1) * WW;
                int d11 = d10 + d01;
                const float* xc = x + xb_base + (size_t)(ch * 32 + clb2) * HW;
                v0 = ww.x * xc[off00]       + ww.y * xc[off00 + d01]
                   + ww.z * xc[off00 + d10] + ww.w * xc[off00 + d11];
                xc += HW;
                v1 = ww.x * xc[off00]       + ww.y * xc[off00 + d01]
                   + ww.z * xc[off00 + d10] + ww.w * xc[off00 + d11];
            }
            *reinterpret_cast<unsigned int*>(&sS[pix * SPITCH + tap * 32 + clb2]) =
                f2bf(v0) | ((unsigned int)f2bf(v1) << 16);
        }
        __syncthreads();                  // sS ready; sT fully consumed

        // ---- issue next chunk's tile DMA (hides under MFMA) ----
        if (ch < 7) {
            const float* gb = gx_base + (size_t)(ch + 1) * 32 * HW;
#pragma unroll
            for (int i = 0; i < 4; ++i)
                if (wv + i * 8 < NST5)
                    GLOAD_LDS16(gb + srcOff5[i], (char*)sT + (wv + i * 8) * 1024);
            __builtin_amdgcn_sched_barrier(0);
        }

        // ---- MFMA: wave wv computes o in [wv*32, wv*32+32) ----
        const int kb_base = ch * 36;
        const bf16x8* wAv = reinterpret_cast<const bf16x8*>(wA);
#pragma unroll 1
        for (int ks = 0; ks < 9; ++ks) {
            bf16x8 bfr[2];
#pragma unroll
            for (int nf = 0; nf < 2; ++nf)
                bfr[nf] = *reinterpret_cast<const bf16x8*>(
                    &sS[(nf * 16 + lm) * SPITCH + ks * 32 + lq * 8]);
#pragma unroll
            for (int mf = 0; mf < 2; ++mf) {
                int o  = wv * 32 + mf * 16 + lm;
                int kb = kb_base + ks * 4 + lq;
                bf16x8 af = wAv[(size_t)kb * 256 + o];
#pragma unroll
                for (int nf = 0; nf < 2; ++nf)
                    acc[mf][nf] = __builtin_amdgcn_mfma_f32_16x16x32_bf16(
                        af, bfr[nf], acc[mf][nf], 0, 0, 0);
            }
        }
        __syncthreads();        // MFMA done (sS free) + next tile DMA drained
    }

    // ---- epilogue: D row = lq*4 + r, col = lm ----
#pragma unroll
    for (int mf = 0; mf < 2; ++mf) {
#pragma unroll
        for (int r = 0; r < 4; ++r) {
            int o = wv * 32 + mf * 16 + lq * 4 + r;
            float bo = b_dc[o];
#pragma unroll
            for (int nf = 0; nf < 2; ++nf) {
                int p = nf * 16 + lm;
                out[((size_t)(b * 256 + o)) * HW + h * WW + w0 + p] = acc[mf][nf][r] + bo;
            }
        }
    }
}

extern "C" void kernel_launch(void* const* d_in, const int* in_sizes, int n_in,
                              void* d_out, int out_size, void* d_ws, size_t ws_size,
                              hipStream_t stream) {
    const float* x    = (const float*)d_in[0];
    const float* w_om = (const float*)d_in[1];
    const float* b_om = (const float*)d_in[2];
    const float* w_dc = (const float*)d_in[3];
    const float* b_dc = (const float*)d_in[4];
    float* out = (float*)d_out;

    unsigned short* wA   = (unsigned short*)d_ws;                    // 1,179,648 B
    unsigned short* wOmA = (unsigned short*)((char*)d_ws + 1179648); //   147,456 B

    wprep_kernel<<<(256 * KTOT) / 256, 256, 0, stream>>>(w_dc, wA);
    womprep_kernel<<<73728 / 256, 256, 0, stream>>>(w_om, wOmA);
    deform_mfma_kernel<<<BB * HH * 2, 512, 0, stream>>>(x, wOmA, b_om, wA, b_dc, out);
}